// Round 3
// baseline (1463.859 us; speedup 1.0000x reference)
//
#include <hip/hip_runtime.h>

#define TT 215
#define BB 256
#define ROWS (TT * BB)  // 55040 = 860 * 64

// ---------------------------------------------------------------- one-shot prep: weight transposes + timescales
__global__ void k_prep(const float* __restrict__ W_enc, const float* __restrict__ Wskip,
                       const float* __restrict__ Wq, const float* __restrict__ Wk,
                       const float* __restrict__ Wv, const float* __restrict__ enc_out_w,
                       const float* __restrict__ ff2_w,
                       float* __restrict__ T_enc, float* __restrict__ T_skip,
                       float* __restrict__ Tq, float* __restrict__ Tk, float* __restrict__ Tv,
                       float* __restrict__ T_out, float* __restrict__ T_ff2,
                       float* __restrict__ ts) {
    int g = blockIdx.x * 256 + threadIdx.x;
    if (g < 18) ts[g] = (float)pow(215.0, (double)g / 17.0);  // matches np float64 215**linspace
    if (g < 1296) {
        int r = g / 36, c = g % 36;
        T_enc[c * 36 + r] = W_enc[g];
        T_skip[c * 36 + r] = Wskip[g];
        Tq[c * 36 + r] = Wq[g];
        Tk[c * 36 + r] = Wk[g];
        Tv[c * 36 + r] = Wv[g];
    }
    if (g < 2 * 5184) {  // enc_out_w [2][72][72] -> [2][i][o]
        int l = g / 5184, e = g % 5184;
        int r = e / 72, c = e % 72;
        T_out[l * 5184 + c * 72 + r] = enc_out_w[g];
    }
    if (g < 2 * 9216) {  // ff2 [2][72][128] -> [2][j][o]
        int l = g / 9216, e = g % 9216;
        int o = e / 128, j = e % 128;
        T_ff2[l * 9216 + j * 72 + o] = ff2_w[g];
    }
}

// ---------------------------------------------------------------- fused: x=(src@We.T+b)*6 ; h=[x@Ws.T+b | pe]
__global__ __launch_bounds__(256, 3) void k_encode(const float* __restrict__ src,
                                                   const float* __restrict__ times,
                                                   const float* __restrict__ T_enc,
                                                   const float* __restrict__ b_enc,
                                                   const float* __restrict__ T_skip,
                                                   const float* __restrict__ bskip,
                                                   const float* __restrict__ ts,
                                                   float* __restrict__ x, float* __restrict__ h) {
    int row = blockIdx.x * 256 + threadIdx.x;
    float s[36];
    const float4* sv = (const float4*)(src + (size_t)row * 72);
#pragma unroll
    for (int k = 0; k < 9; ++k) {
        float4 v = sv[k];
        s[4 * k] = v.x; s[4 * k + 1] = v.y; s[4 * k + 2] = v.z; s[4 * k + 3] = v.w;
    }
    float xr[36];
#pragma unroll
    for (int o = 0; o < 36; ++o) xr[o] = b_enc[o];
#pragma unroll
    for (int i = 0; i < 36; ++i) {
#pragma unroll
        for (int o = 0; o < 36; ++o) xr[o] = fmaf(s[i], T_enc[i * 36 + o], xr[o]);
    }
#pragma unroll
    for (int o = 0; o < 36; ++o) xr[o] *= 6.0f;
    if (blockIdx.x < 36) {  // only rows t<36 are consumed by the graph stage
        float4* xv = (float4*)(x + (size_t)row * 36);
#pragma unroll
        for (int k = 0; k < 9; ++k)
            xv[k] = make_float4(xr[4 * k], xr[4 * k + 1], xr[4 * k + 2], xr[4 * k + 3]);
    }
    float acc[36];
#pragma unroll
    for (int o = 0; o < 36; ++o) acc[o] = bskip[o];
#pragma unroll
    for (int i = 0; i < 36; ++i) {
#pragma unroll
        for (int o = 0; o < 36; ++o) acc[o] = fmaf(xr[i], T_skip[i * 36 + o], acc[o]);
    }
    float* hr = h + (size_t)row * 72;
    float4* hv = (float4*)hr;
#pragma unroll
    for (int k = 0; k < 9; ++k)
        hv[k] = make_float4(acc[4 * k], acc[4 * k + 1], acc[4 * k + 2], acc[4 * k + 3]);
    float t = times[row];
#pragma unroll
    for (int d = 0; d < 18; ++d) {
        float sc = t / ts[d];
        hr[36 + d] = sinf(sc);
        hr[54 + d] = cosf(sc);
    }
}

// ---------------------------------------------------------------- graph q|k|v (blockIdx.y selects matrix)
__global__ __launch_bounds__(256, 4) void k_graph_qkv(const float* __restrict__ x,
                                                      const float* __restrict__ Tq, const float* __restrict__ bq,
                                                      const float* __restrict__ Tk, const float* __restrict__ bk,
                                                      const float* __restrict__ Tv, const float* __restrict__ bv,
                                                      float* __restrict__ qg, float* __restrict__ kg,
                                                      float* __restrict__ vg) {
    int row = blockIdx.x * 256 + threadIdx.x;  // < 9216
    const float* TW; const float* bias; float* out;
    if (blockIdx.y == 0)      { TW = Tq; bias = bq; out = qg; }
    else if (blockIdx.y == 1) { TW = Tk; bias = bk; out = kg; }
    else                      { TW = Tv; bias = bv; out = vg; }
    float xr[36];
    const float4* xv = (const float4*)(x + (size_t)row * 36);
#pragma unroll
    for (int k = 0; k < 9; ++k) {
        float4 v = xv[k];
        xr[4 * k] = v.x; xr[4 * k + 1] = v.y; xr[4 * k + 2] = v.z; xr[4 * k + 3] = v.w;
    }
    float acc[36];
#pragma unroll
    for (int o = 0; o < 36; ++o) acc[o] = bias[o];
#pragma unroll
    for (int i = 0; i < 36; ++i) {
#pragma unroll
        for (int o = 0; o < 36; ++o) acc[o] = fmaf(xr[i], TW[i * 36 + o], acc[o]);
    }
    float4* ov = (float4*)(out + (size_t)row * 36);
#pragma unroll
    for (int k = 0; k < 9; ++k)
        ov[k] = make_float4(acc[4 * k], acc[4 * k + 1], acc[4 * k + 2], acc[4 * k + 3]);
}

// ---------------------------------------------------------------- graph attention per batch; h[:36,:,:36] += msg
__global__ void k_graph_attn(const float* __restrict__ qg, const float* __restrict__ kg,
                             const float* __restrict__ vg, float* __restrict__ h,
                             float* __restrict__ Abuf, float* __restrict__ sqv) {
    __shared__ float q[1296], k[1296], v[1296], A[1296];
    __shared__ float red[128];
    int b = blockIdx.x, tid = threadIdx.x;
    for (int i = tid; i < 1296; i += 128) {
        int t = i / 36, e = i % 36;
        int g = (t * BB + b) * 36 + e;
        q[i] = qg[g]; k[i] = kg[g]; v[i] = vg[g];
    }
    __syncthreads();
    for (int i = tid; i < 1296; i += 128) {
        int r = i / 36, c = i % 36;
        float a = 0.f;
#pragma unroll
        for (int e = 0; e < 36; ++e) a = fmaf(q[r * 36 + e], k[c * 36 + e], a);
        A[i] = a * (1.0f / 6.0f);
    }
    __syncthreads();
    if (tid < 36) {
        float m = -1e30f;
        for (int j = 0; j < 36; ++j) m = fmaxf(m, A[tid * 36 + j]);
        float s = 0.f;
        for (int j = 0; j < 36; ++j) { float e = expf(A[tid * 36 + j] - m); A[tid * 36 + j] = e; s += e; }
        float inv = 1.0f / s;
        for (int j = 0; j < 36; ++j) A[tid * 36 + j] *= inv;
    }
    __syncthreads();
    float lsq = 0.f;
    for (int i = tid; i < 1296; i += 128) {
        float a = A[i];
        Abuf[(size_t)b * 1296 + i] = a;
        lsq = fmaf(a, a, lsq);
        int r = i / 36, e = i % 36;
        float m = 0.f;
#pragma unroll
        for (int j = 0; j < 36; ++j) m = fmaf(A[r * 36 + j], v[j * 36 + e], m);
        h[((size_t)r * BB + b) * 72 + e] += m;
    }
    red[tid] = lsq;
    __syncthreads();
    for (int s = 64; s > 0; s >>= 1) { if (tid < s) red[tid] += red[tid + s]; __syncthreads(); }
    if (tid == 0) sqv[b] = red[0];
}

// ---------------------------------------------------------------- Gram row + per-row distance partial sum
__global__ void k_gram(const float* __restrict__ Abuf, const float* __restrict__ sqv,
                       float* __restrict__ rowsum) {
    __shared__ float Arow[1296];
    __shared__ float red[256];
    int b1 = blockIdx.x, tid = threadIdx.x;
    for (int i = tid; i < 1296; i += 256) Arow[i] = Abuf[(size_t)b1 * 1296 + i];
    __syncthreads();
    int b2 = tid;
    const float* a2 = Abuf + (size_t)b2 * 1296;
    float dot = 0.f;
    for (int e = 0; e < 1296; ++e) dot = fmaf(Arow[e], a2[e], dot);
    float d2 = fmaxf(sqv[b1] + sqv[b2] - 2.0f * dot, 0.0f);
    red[tid] = (d2 > 0.0f) ? sqrtf(d2) : 0.0f;
    __syncthreads();
    for (int s = 128; s > 0; s >>= 1) { if (tid < s) red[tid] += red[tid + s]; __syncthreads(); }
    if (tid == 0) rowsum[b1] = red[0];
}

// ---------------------------------------------------------------- qkv = h @ W_in.T + b_in ; grid (215,4), 54 outs/block
__global__ __launch_bounds__(256, 4) void k_qkv(const float* __restrict__ h, const float* __restrict__ W,
                                                const float* __restrict__ bias, float* __restrict__ qkv) {
    int row = blockIdx.x * 256 + threadIdx.x;
    int o0 = blockIdx.y * 54;
    float hr[72];
    const float4* hv = (const float4*)(h + (size_t)row * 72);
#pragma unroll
    for (int k = 0; k < 18; ++k) {
        float4 v = hv[k];
        hr[4 * k] = v.x; hr[4 * k + 1] = v.y; hr[4 * k + 2] = v.z; hr[4 * k + 3] = v.w;
    }
    float* qr = qkv + (size_t)row * 216;
    for (int c = 0; c < 9; ++c) {  // 9 chunks x 6 outputs
        int j0 = o0 + c * 6;
        float a[6];
#pragma unroll
        for (int k = 0; k < 6; ++k) {
            float acc = bias[j0 + k];
            const float* w = W + (size_t)(j0 + k) * 72;
#pragma unroll
            for (int i = 0; i < 72; ++i) acc = fmaf(hr[i], w[i], acc);
            a[k] = acc;
        }
        float2* qv = (float2*)(qr + j0);
        qv[0] = make_float2(a[0], a[1]);
        qv[1] = make_float2(a[2], a[3]);
        qv[2] = make_float2(a[4], a[5]);
    }
}

// ---------------------------------------------------------------- masked MHA, block = (b, head), thread = query row
__global__ __launch_bounds__(256) void k_attn(const float* __restrict__ qkv,
                                              const int* __restrict__ lengths,
                                              float* __restrict__ ctx) {
    __shared__ float Ks[TT * 20];
    __shared__ float Vs[TT * 20];
    int b = blockIdx.x & (BB - 1);
    int hh = blockIdx.x >> 8;
    int tid = threadIdx.x;
    int len = lengths[b];
    for (int i = tid; i < TT * 20; i += 256) {
        int s = i / 20, d = i % 20;
        float kk = 0.f, vv = 0.f;
        if (d < 18) {
            size_t base = ((size_t)s * BB + b) * 216 + hh * 18 + d;
            kk = qkv[base + 72];
            vv = qkv[base + 144];
        }
        Ks[i] = kk; Vs[i] = vv;
    }
    __syncthreads();
    if (tid >= TT) return;
    float q[20];
    q[18] = 0.f; q[19] = 0.f;
    {
        const float* qb = qkv + ((size_t)tid * BB + b) * 216 + hh * 18;
#pragma unroll
        for (int d = 0; d < 18; ++d) q[d] = qb[d];
    }
    const float scale = 0.23570226039551587f;  // 1/sqrt(18)
    float m = -1e30f, l = 0.f;
    float acc[20];
#pragma unroll
    for (int d = 0; d < 20; ++d) acc[d] = 0.f;
    for (int s = 0; s < len; ++s) {
        const float4* kp = (const float4*)(Ks + s * 20);
        float sc = 0.f;
#pragma unroll
        for (int c = 0; c < 5; ++c) {
            float4 kv = kp[c];
            sc = fmaf(q[4 * c], kv.x, sc);
            sc = fmaf(q[4 * c + 1], kv.y, sc);
            sc = fmaf(q[4 * c + 2], kv.z, sc);
            sc = fmaf(q[4 * c + 3], kv.w, sc);
        }
        sc *= scale;
        float mn = fmaxf(m, sc);
        float alpha = __expf(m - mn);
        float p = __expf(sc - mn);
        l = l * alpha + p;
        const float4* vp = (const float4*)(Vs + s * 20);
#pragma unroll
        for (int c = 0; c < 5; ++c) {
            float4 vv = vp[c];
            acc[4 * c]     = fmaf(acc[4 * c], alpha, p * vv.x);
            acc[4 * c + 1] = fmaf(acc[4 * c + 1], alpha, p * vv.y);
            acc[4 * c + 2] = fmaf(acc[4 * c + 2], alpha, p * vv.z);
            acc[4 * c + 3] = fmaf(acc[4 * c + 3], alpha, p * vv.w);
        }
        m = mn;
    }
    float inv = 1.0f / l;
    float* cb = ctx + ((size_t)tid * BB + b) * 72 + hh * 18;
#pragma unroll
    for (int d = 0; d < 18; ++d) cb[d] = acc[d] * inv;
}

// ---------------------------------------------------------------- h = LN(h + ctx@Wout.T+b) ; 64 rows x 4 waves
__global__ __launch_bounds__(256, 4) void k_outln(const float* __restrict__ ctx,
                                                  const float* __restrict__ TW,
                                                  const float* __restrict__ bias,
                                                  const float* __restrict__ g,
                                                  const float* __restrict__ beta,
                                                  float* __restrict__ h) {
    __shared__ float hls[64][73];
    __shared__ float cls[64][73];
    __shared__ float ps[4][64], pq[4][64];
    int tid = threadIdx.x;
    int w = tid >> 6, r = tid & 63;
    size_t base = (size_t)blockIdx.x * 64 * 72;
    for (int idx = tid; idx < 64 * 72; idx += 256) {
        int rr = idx / 72, cc = idx % 72;
        hls[rr][cc] = h[base + idx];
        cls[rr][cc] = ctx[base + idx];
    }
    __syncthreads();
    int o0 = w * 18;
    float acc[18];
#pragma unroll
    for (int o = 0; o < 18; ++o) acc[o] = bias[o0 + o];
    for (int i = 0; i < 72; ++i) {
        float ci = cls[r][i];
        const float* tw = TW + i * 72 + o0;
#pragma unroll
        for (int o = 0; o < 18; ++o) acc[o] = fmaf(ci, tw[o], acc[o]);
    }
    float s = 0.f, q = 0.f;
#pragma unroll
    for (int o = 0; o < 18; ++o) {
        acc[o] += hls[r][o0 + o];
        s += acc[o];
        q = fmaf(acc[o], acc[o], q);
    }
    ps[w][r] = s; pq[w][r] = q;
    __syncthreads();
    float st = ps[0][r] + ps[1][r] + ps[2][r] + ps[3][r];
    float qt = pq[0][r] + pq[1][r] + pq[2][r] + pq[3][r];
    float mu = st / 72.0f;
    float var = fmaxf(qt / 72.0f - mu * mu, 0.0f);
    float rstd = 1.0f / sqrtf(var + 1e-5f);
    float* hr = h + base + (size_t)r * 72 + o0;
#pragma unroll
    for (int o = 0; o < 18; ++o) hr[o] = (acc[o] - mu) * rstd * g[o0 + o] + beta[o0 + o];
}

// ---------------------------------------------------------------- h = LN(h + relu(h@ff1.T)@ff2.T+b) ; 64 rows x 4 waves
__global__ __launch_bounds__(256, 3) void k_ffln(const float* __restrict__ ff1,
                                                 const float* __restrict__ b1,
                                                 const float* __restrict__ Tff2,
                                                 const float* __restrict__ b2,
                                                 const float* __restrict__ g,
                                                 const float* __restrict__ beta,
                                                 float* __restrict__ h) {
    __shared__ float hls[64][73];
    __shared__ float hid[64][129];
    __shared__ float ps[4][64], pq[4][64];
    int tid = threadIdx.x;
    int w = tid >> 6, r = tid & 63;
    size_t base = (size_t)blockIdx.x * 64 * 72;
    for (int idx = tid; idx < 64 * 72; idx += 256) {
        int rr = idx / 72, cc = idx % 72;
        hls[rr][cc] = h[base + idx];
    }
    __syncthreads();
    float hr[72];
#pragma unroll
    for (int i = 0; i < 72; ++i) hr[i] = hls[r][i];
    int j0 = w * 32;
    for (int j = j0; j < j0 + 32; ++j) {
        float a = b1[j];
        const float* wp = ff1 + (size_t)j * 72;
#pragma unroll
        for (int i = 0; i < 72; ++i) a = fmaf(hr[i], wp[i], a);
        hid[r][j] = fmaxf(a, 0.f);
    }
    __syncthreads();
    int o0 = w * 18;
    float acc[18];
#pragma unroll
    for (int o = 0; o < 18; ++o) acc[o] = b2[o0 + o];
    for (int j = 0; j < 128; ++j) {
        float hj = hid[r][j];
        const float* wt = Tff2 + (size_t)j * 72 + o0;
#pragma unroll
        for (int o = 0; o < 18; ++o) acc[o] = fmaf(hj, wt[o], acc[o]);
    }
    float s = 0.f, q = 0.f;
#pragma unroll
    for (int o = 0; o < 18; ++o) {
        acc[o] += hls[r][o0 + o];
        s += acc[o];
        q = fmaf(acc[o], acc[o], q);
    }
    ps[w][r] = s; pq[w][r] = q;
    __syncthreads();
    float st = ps[0][r] + ps[1][r] + ps[2][r] + ps[3][r];
    float qt = pq[0][r] + pq[1][r] + pq[2][r] + pq[3][r];
    float mu = st / 72.0f;
    float var = fmaxf(qt / 72.0f - mu * mu, 0.0f);
    float rstd = 1.0f / sqrtf(var + 1e-5f);
    float* hp = h + base + (size_t)r * 72 + o0;
#pragma unroll
    for (int o = 0; o < 18; ++o) hp[o] = (acc[o] - mu) * rstd * g[o0 + o] + beta[o0 + o];
}

// ---------------------------------------------------------------- masked mean-pool + static emb + 2-layer MLP
__global__ void k_head(const float* __restrict__ h, const int* __restrict__ lengths,
                       const float* __restrict__ statics, const float* __restrict__ W_emb,
                       const float* __restrict__ b_emb, const float* __restrict__ w1,
                       const float* __restrict__ bb1, const float* __restrict__ w2,
                       const float* __restrict__ bb2, float* __restrict__ out) {
    __shared__ float ps2[4][72];
    __shared__ float feat[108];
    __shared__ float hidm[108];
    __shared__ float st[9];
    int b = blockIdx.x, tid = threadIdx.x;
    int w = tid >> 6, lane = tid & 63;
    int len = lengths[b];
    if (tid < 9) st[tid] = statics[b * 9 + tid];
    for (int idx = tid; idx < 288; idx += 256) ((float*)ps2)[idx] = 0.f;
    __syncthreads();
#pragma unroll
    for (int c0 = 0; c0 < 128; c0 += 64) {
        int col = c0 + lane;
        if (col < 72) {
            float s = 0.f;
            for (int t = w; t < len; t += 4) s += h[((size_t)t * BB + b) * 72 + col];
            ps2[w][col] = s;
        }
    }
    __syncthreads();
    if (tid < 72)
        feat[tid] = (ps2[0][tid] + ps2[1][tid] + ps2[2][tid] + ps2[3][tid]) / ((float)len + 1.0f);
    if (tid >= 128 && tid < 164) {
        int o = tid - 128;
        float a = b_emb[o];
#pragma unroll
        for (int i = 0; i < 9; ++i) a = fmaf(st[i], W_emb[o * 9 + i], a);
        feat[72 + o] = a;
    }
    __syncthreads();
    if (tid < 108) {
        float a = bb1[tid];
        for (int i = 0; i < 108; ++i) a = fmaf(feat[i], w1[tid * 108 + i], a);
        hidm[tid] = fmaxf(a, 0.f);
    }
    __syncthreads();
    if (tid < 2) {
        float a = bb2[tid];
        for (int i = 0; i < 108; ++i) a = fmaf(hidm[i], w2[tid * 108 + i], a);
        out[b * 2 + tid] = a;
    }
}

// ---------------------------------------------------------------- final distance reduce
__global__ void k_dist(const float* __restrict__ rowsum, float* __restrict__ out) {
    __shared__ float red[256];
    int tid = threadIdx.x;
    red[tid] = rowsum[tid];
    __syncthreads();
    for (int s = 128; s > 0; s >>= 1) { if (tid < s) red[tid] += red[tid + s]; __syncthreads(); }
    if (tid == 0) out[2 * BB] = red[0] / 65536.0f;
}

extern "C" void kernel_launch(void* const* d_in, const int* in_sizes, int n_in,
                              void* d_out, int out_size, void* d_ws, size_t ws_size,
                              hipStream_t stream) {
    const float* src     = (const float*)d_in[0];
    const float* statics = (const float*)d_in[1];
    const float* times   = (const float*)d_in[2];
    const int*   lengths = (const int*)d_in[3];
    const float* W_enc = (const float*)d_in[4];  const float* b_enc = (const float*)d_in[5];
    const float* W_emb = (const float*)d_in[6];  const float* b_emb = (const float*)d_in[7];
    const float* Wq = (const float*)d_in[8];     const float* bq = (const float*)d_in[9];
    const float* Wk = (const float*)d_in[10];    const float* bk = (const float*)d_in[11];
    const float* Wv = (const float*)d_in[12];    const float* bv = (const float*)d_in[13];
    const float* Wskip = (const float*)d_in[14]; const float* bskip = (const float*)d_in[15];
    const float* enc_in_w = (const float*)d_in[16];  const float* enc_in_b = (const float*)d_in[17];
    const float* enc_out_w = (const float*)d_in[18]; const float* enc_out_b = (const float*)d_in[19];
    const float* ff1_w = (const float*)d_in[20]; const float* ff1_b = (const float*)d_in[21];
    const float* ff2_w = (const float*)d_in[22]; const float* ff2_b = (const float*)d_in[23];
    const float* ln1_g = (const float*)d_in[24]; const float* ln1_b = (const float*)d_in[25];
    const float* ln2_g = (const float*)d_in[26]; const float* ln2_b = (const float*)d_in[27];
    const float* w1 = (const float*)d_in[28];    const float* bb1 = (const float*)d_in[29];
    const float* w2 = (const float*)d_in[30];    const float* bb2 = (const float*)d_in[31];
    float* out = (float*)d_out;

    float* p = (float*)d_ws;
    float* x    = p; p += (size_t)36 * BB * 36;
    float* h    = p; p += (size_t)ROWS * 72;
    float* qkv  = p; p += (size_t)ROWS * 216;
    float* ctx  = p; p += (size_t)ROWS * 72;
    float* qg   = p; p += (size_t)36 * BB * 36;
    float* kg   = p; p += (size_t)36 * BB * 36;
    float* vg   = p; p += (size_t)36 * BB * 36;
    float* Abuf = p; p += (size_t)BB * 1296;
    float* sqv  = p; p += BB;
    float* rsum = p; p += BB;
    float* ts   = p; p += 32;
    float* T_enc  = p; p += 1296;
    float* T_skip = p; p += 1296;
    float* Tq     = p; p += 1296;
    float* Tk     = p; p += 1296;
    float* Tv     = p; p += 1296;
    float* T_out  = p; p += 2 * 5184;
    float* T_ff2  = p; p += 2 * 9216;

    k_prep<<<72, 256, 0, stream>>>(W_enc, Wskip, Wq, Wk, Wv, enc_out_w, ff2_w,
                                   T_enc, T_skip, Tq, Tk, Tv, T_out, T_ff2, ts);
    k_encode<<<TT, 256, 0, stream>>>(src, times, T_enc, b_enc, T_skip, bskip, ts, x, h);
    k_graph_qkv<<<dim3(36, 3), 256, 0, stream>>>(x, Tq, bq, Tk, bk, Tv, bv, qg, kg, vg);
    k_graph_attn<<<BB, 128, 0, stream>>>(qg, kg, vg, h, Abuf, sqv);
    k_gram<<<BB, 256, 0, stream>>>(Abuf, sqv, rsum);
    for (int l = 0; l < 2; ++l) {
        k_qkv<<<dim3(TT, 4), 256, 0, stream>>>(h, enc_in_w + (size_t)l * 216 * 72,
                                               enc_in_b + l * 216, qkv);
        k_attn<<<BB * 4, 256, 0, stream>>>(qkv, lengths, ctx);
        k_outln<<<ROWS / 64, 256, 0, stream>>>(ctx, T_out + (size_t)l * 5184, enc_out_b + l * 72,
                                               ln1_g + l * 72, ln1_b + l * 72, h);
        k_ffln<<<ROWS / 64, 256, 0, stream>>>(ff1_w + (size_t)l * 128 * 72, ff1_b + l * 128,
                                              T_ff2 + (size_t)l * 9216, ff2_b + l * 72,
                                              ln2_g + l * 72, ln2_b + l * 72, h);
    }
    k_head<<<BB, 256, 0, stream>>>(h, lengths, statics, W_emb, b_emb, w1, bb1, w2, bb2, out);
    k_dist<<<1, 256, 0, stream>>>(rsum, out);
}

// Round 4
// 1402.586 us; speedup vs baseline: 1.0437x; 1.0437x over previous
//
#include <hip/hip_runtime.h>

#define TT 215
#define BB 256
#define ROWS (TT * BB)  // 55040 = 860 * 64

// ---------------------------------------------------------------- one-shot prep: ff2 transpose + timescales
__global__ void k_prep(const float* __restrict__ ff2_w, float* __restrict__ T_ff2,
                       float* __restrict__ ts) {
    int g = blockIdx.x * 256 + threadIdx.x;
    if (g < 18) ts[g] = (float)pow(215.0, (double)g / 17.0);  // matches np float64 215**linspace
    if (g < 2 * 9216) {  // ff2 [2][72][128] -> [2][j][o]
        int l = g / 9216, e = g % 9216;
        int o = e / 128, j = e % 128;
        T_ff2[l * 9216 + j * 72 + o] = ff2_w[g];
    }
}

// ---------------------------------------------------------------- x = (src[:,:,:36] @ W_enc.T + b)*6 ; grid (215,4)
__global__ __launch_bounds__(256, 4) void k_enc1(const float* __restrict__ src,
                                                 const float* __restrict__ W,
                                                 const float* __restrict__ bias,
                                                 float* __restrict__ x) {
    int row = blockIdx.x * 256 + threadIdx.x;
    int o0 = blockIdx.y * 9;
    float s[36];
    const float4* sv = (const float4*)(src + (size_t)row * 72);
#pragma unroll
    for (int k = 0; k < 9; ++k) {
        float4 v = sv[k];
        s[4 * k] = v.x; s[4 * k + 1] = v.y; s[4 * k + 2] = v.z; s[4 * k + 3] = v.w;
    }
    float acc[9];
#pragma unroll
    for (int o = 0; o < 9; ++o) {
        float a = bias[o0 + o];
        const float* w = W + (size_t)(o0 + o) * 36;
#pragma unroll
        for (int i = 0; i < 36; ++i) a = fmaf(s[i], w[i], a);
        acc[o] = a * 6.0f;
    }
    float* xp = x + (size_t)row * 36 + o0;
#pragma unroll
    for (int o = 0; o < 9; ++o) xp[o] = acc[o];
}

// ---------------------------------------------------------------- h[:,:, :36] = x @ Wskip.T + b ; grid (215,4)
__global__ __launch_bounds__(256, 4) void k_enc2(const float* __restrict__ x,
                                                 const float* __restrict__ W,
                                                 const float* __restrict__ bias,
                                                 float* __restrict__ h) {
    int row = blockIdx.x * 256 + threadIdx.x;
    int o0 = blockIdx.y * 9;
    float xr[36];
    const float4* xv = (const float4*)(x + (size_t)row * 36);
#pragma unroll
    for (int k = 0; k < 9; ++k) {
        float4 v = xv[k];
        xr[4 * k] = v.x; xr[4 * k + 1] = v.y; xr[4 * k + 2] = v.z; xr[4 * k + 3] = v.w;
    }
    float* hp = h + (size_t)row * 72 + o0;
#pragma unroll
    for (int o = 0; o < 9; ++o) {
        float a = bias[o0 + o];
        const float* w = W + (size_t)(o0 + o) * 36;
#pragma unroll
        for (int i = 0; i < 36; ++i) a = fmaf(xr[i], w[i], a);
        hp[o] = a;
    }
}

// ---------------------------------------------------------------- h[:,:,36:] = pe ; elementwise
__global__ __launch_bounds__(256) void k_pe(const float* __restrict__ times,
                                            const float* __restrict__ ts,
                                            float* __restrict__ h) {
    int idx = blockIdx.x * 256 + threadIdx.x;  // < ROWS*36
    int d = idx % 36, row = idx / 36;
    float t = times[row];
    float val;
    if (d < 18) val = sinf(t / ts[d]);
    else        val = cosf(t / ts[d - 18]);
    h[(size_t)row * 72 + 36 + d] = val;
}

// ---------------------------------------------------------------- graph q|k|v ; grid (36, 12): mat = y>>2, o0 = (y&3)*9
__global__ __launch_bounds__(256, 4) void k_graph_qkv(const float* __restrict__ x,
                                                      const float* __restrict__ Wq, const float* __restrict__ bq,
                                                      const float* __restrict__ Wk, const float* __restrict__ bk,
                                                      const float* __restrict__ Wv, const float* __restrict__ bv,
                                                      float* __restrict__ qg, float* __restrict__ kg,
                                                      float* __restrict__ vg) {
    int row = blockIdx.x * 256 + threadIdx.x;  // < 9216
    int mat = blockIdx.y >> 2;
    int o0 = (blockIdx.y & 3) * 9;
    const float* W; const float* bias; float* out;
    if (mat == 0)      { W = Wq; bias = bq; out = qg; }
    else if (mat == 1) { W = Wk; bias = bk; out = kg; }
    else               { W = Wv; bias = bv; out = vg; }
    float xr[36];
    const float4* xv = (const float4*)(x + (size_t)row * 36);
#pragma unroll
    for (int k = 0; k < 9; ++k) {
        float4 v = xv[k];
        xr[4 * k] = v.x; xr[4 * k + 1] = v.y; xr[4 * k + 2] = v.z; xr[4 * k + 3] = v.w;
    }
    float* op = out + (size_t)row * 36 + o0;
#pragma unroll
    for (int o = 0; o < 9; ++o) {
        float a = bias[o0 + o];
        const float* w = W + (size_t)(o0 + o) * 36;
#pragma unroll
        for (int i = 0; i < 36; ++i) a = fmaf(xr[i], w[i], a);
        op[o] = a;
    }
}

// ---------------------------------------------------------------- graph attention per batch; h[:36,:,:36] += msg
__global__ void k_graph_attn(const float* __restrict__ qg, const float* __restrict__ kg,
                             const float* __restrict__ vg, float* __restrict__ h,
                             float* __restrict__ Abuf, float* __restrict__ sqv) {
    __shared__ float q[1296], k[1296], v[1296], A[1296];
    __shared__ float red[128];
    int b = blockIdx.x, tid = threadIdx.x;
    for (int i = tid; i < 1296; i += 128) {
        int t = i / 36, e = i % 36;
        int g = (t * BB + b) * 36 + e;
        q[i] = qg[g]; k[i] = kg[g]; v[i] = vg[g];
    }
    __syncthreads();
    for (int i = tid; i < 1296; i += 128) {
        int r = i / 36, c = i % 36;
        float a = 0.f;
#pragma unroll
        for (int e = 0; e < 36; ++e) a = fmaf(q[r * 36 + e], k[c * 36 + e], a);
        A[i] = a * (1.0f / 6.0f);
    }
    __syncthreads();
    if (tid < 36) {
        float m = -1e30f;
        for (int j = 0; j < 36; ++j) m = fmaxf(m, A[tid * 36 + j]);
        float s = 0.f;
        for (int j = 0; j < 36; ++j) { float e = expf(A[tid * 36 + j] - m); A[tid * 36 + j] = e; s += e; }
        float inv = 1.0f / s;
        for (int j = 0; j < 36; ++j) A[tid * 36 + j] *= inv;
    }
    __syncthreads();
    float lsq = 0.f;
    for (int i = tid; i < 1296; i += 128) {
        float a = A[i];
        Abuf[(size_t)b * 1296 + i] = a;
        lsq = fmaf(a, a, lsq);
        int r = i / 36, e = i % 36;
        float m = 0.f;
#pragma unroll
        for (int j = 0; j < 36; ++j) m = fmaf(A[r * 36 + j], v[j * 36 + e], m);
        h[((size_t)r * BB + b) * 72 + e] += m;
    }
    red[tid] = lsq;
    __syncthreads();
    for (int s = 64; s > 0; s >>= 1) { if (tid < s) red[tid] += red[tid + s]; __syncthreads(); }
    if (tid == 0) sqv[b] = red[0];
}

// ---------------------------------------------------------------- Gram row + per-row distance partial sum
__global__ void k_gram(const float* __restrict__ Abuf, const float* __restrict__ sqv,
                       float* __restrict__ rowsum) {
    __shared__ float Arow[1296];
    __shared__ float red[256];
    int b1 = blockIdx.x, tid = threadIdx.x;
    for (int i = tid; i < 1296; i += 256) Arow[i] = Abuf[(size_t)b1 * 1296 + i];
    __syncthreads();
    int b2 = tid;
    const float* a2 = Abuf + (size_t)b2 * 1296;
    float dot = 0.f;
    for (int e = 0; e < 1296; ++e) dot = fmaf(Arow[e], a2[e], dot);
    float d2 = fmaxf(sqv[b1] + sqv[b2] - 2.0f * dot, 0.0f);
    red[tid] = (d2 > 0.0f) ? sqrtf(d2) : 0.0f;
    __syncthreads();
    for (int s = 128; s > 0; s >>= 1) { if (tid < s) red[tid] += red[tid + s]; __syncthreads(); }
    if (tid == 0) rowsum[b1] = red[0];
}

// ---------------------------------------------------------------- qkv = h @ W_in.T + b_in ; grid (215,8), 27 outs
__global__ __launch_bounds__(256, 4) void k_qkv(const float* __restrict__ h, const float* __restrict__ W,
                                                const float* __restrict__ bias, float* __restrict__ qkv) {
    int row = blockIdx.x * 256 + threadIdx.x;
    int o0 = blockIdx.y * 27;
    float hr[72];
    const float4* hv = (const float4*)(h + (size_t)row * 72);
#pragma unroll
    for (int k = 0; k < 18; ++k) {
        float4 v = hv[k];
        hr[4 * k] = v.x; hr[4 * k + 1] = v.y; hr[4 * k + 2] = v.z; hr[4 * k + 3] = v.w;
    }
    float* qr = qkv + (size_t)row * 216 + o0;
#pragma unroll
    for (int o = 0; o < 27; ++o) {
        float a = bias[o0 + o];
        const float* w = W + (size_t)(o0 + o) * 72;
#pragma unroll
        for (int i = 0; i < 72; ++i) a = fmaf(hr[i], w[i], a);
        qr[o] = a;
    }
}

// ---------------------------------------------------------------- masked MHA, block = (b, head), thread = query row
__global__ __launch_bounds__(256) void k_attn(const float* __restrict__ qkv,
                                              const int* __restrict__ lengths,
                                              float* __restrict__ ctx) {
    __shared__ float Ks[TT * 20];
    __shared__ float Vs[TT * 20];
    int b = blockIdx.x & (BB - 1);
    int hh = blockIdx.x >> 8;
    int tid = threadIdx.x;
    int len = lengths[b];
    for (int i = tid; i < TT * 20; i += 256) {
        int s = i / 20, d = i % 20;
        float kk = 0.f, vv = 0.f;
        if (d < 18) {
            size_t base = ((size_t)s * BB + b) * 216 + hh * 18 + d;
            kk = qkv[base + 72];
            vv = qkv[base + 144];
        }
        Ks[i] = kk; Vs[i] = vv;
    }
    __syncthreads();
    if (tid >= TT) return;
    float q[20];
    q[18] = 0.f; q[19] = 0.f;
    {
        const float* qb = qkv + ((size_t)tid * BB + b) * 216 + hh * 18;
#pragma unroll
        for (int d = 0; d < 18; ++d) q[d] = qb[d];
    }
    const float scale = 0.23570226039551587f;  // 1/sqrt(18)
    float m = -1e30f, l = 0.f;
    float acc[20];
#pragma unroll
    for (int d = 0; d < 20; ++d) acc[d] = 0.f;
    for (int s = 0; s < len; ++s) {
        const float4* kp = (const float4*)(Ks + s * 20);
        float sc = 0.f;
#pragma unroll
        for (int c = 0; c < 5; ++c) {
            float4 kv = kp[c];
            sc = fmaf(q[4 * c], kv.x, sc);
            sc = fmaf(q[4 * c + 1], kv.y, sc);
            sc = fmaf(q[4 * c + 2], kv.z, sc);
            sc = fmaf(q[4 * c + 3], kv.w, sc);
        }
        sc *= scale;
        float mn = fmaxf(m, sc);
        float alpha = __expf(m - mn);
        float p = __expf(sc - mn);
        l = l * alpha + p;
        const float4* vp = (const float4*)(Vs + s * 20);
#pragma unroll
        for (int c = 0; c < 5; ++c) {
            float4 vv = vp[c];
            acc[4 * c]     = fmaf(acc[4 * c], alpha, p * vv.x);
            acc[4 * c + 1] = fmaf(acc[4 * c + 1], alpha, p * vv.y);
            acc[4 * c + 2] = fmaf(acc[4 * c + 2], alpha, p * vv.z);
            acc[4 * c + 3] = fmaf(acc[4 * c + 3], alpha, p * vv.w);
        }
        m = mn;
    }
    float inv = 1.0f / l;
    float* cb = ctx + ((size_t)tid * BB + b) * 72 + hh * 18;
#pragma unroll
    for (int d = 0; d < 18; ++d) cb[d] = acc[d] * inv;
}

// ---------------------------------------------------------------- h = LN(h + ctx@Wout.T+b) ; 64 rows x 4 out-waves
__global__ __launch_bounds__(256, 4) void k_outln(const float* __restrict__ ctx,
                                                  const float* __restrict__ W,
                                                  const float* __restrict__ bias,
                                                  const float* __restrict__ g,
                                                  const float* __restrict__ beta,
                                                  float* __restrict__ h) {
    __shared__ float ps[4][64], pq[4][64];
    int tid = threadIdx.x;
    int w = tid >> 6, r = tid & 63;
    size_t rowid = (size_t)blockIdx.x * 64 + r;
    int o0 = w * 18;
    float cr[72];
    const float4* cv = (const float4*)(ctx + rowid * 72);
#pragma unroll
    for (int k = 0; k < 18; ++k) {
        float4 v = cv[k];
        cr[4 * k] = v.x; cr[4 * k + 1] = v.y; cr[4 * k + 2] = v.z; cr[4 * k + 3] = v.w;
    }
    float acc[18];
#pragma unroll
    for (int o = 0; o < 18; ++o) {
        float a = bias[o0 + o];
        const float* wp = W + (size_t)(o0 + o) * 72;
#pragma unroll
        for (int i = 0; i < 72; ++i) a = fmaf(cr[i], wp[i], a);
        acc[o] = a;
    }
    const float* hres = h + rowid * 72 + o0;
    float s = 0.f, q = 0.f;
#pragma unroll
    for (int o = 0; o < 18; ++o) {
        acc[o] += hres[o];
        s += acc[o];
        q = fmaf(acc[o], acc[o], q);
    }
    ps[w][r] = s; pq[w][r] = q;
    __syncthreads();
    float st = ps[0][r] + ps[1][r] + ps[2][r] + ps[3][r];
    float qt = pq[0][r] + pq[1][r] + pq[2][r] + pq[3][r];
    float mu = st / 72.0f;
    float var = fmaxf(qt / 72.0f - mu * mu, 0.0f);
    float rstd = 1.0f / sqrtf(var + 1e-5f);
    float* hw = h + rowid * 72 + o0;
#pragma unroll
    for (int o = 0; o < 18; ++o) hw[o] = (acc[o] - mu) * rstd * g[o0 + o] + beta[o0 + o];
}

// ---------------------------------------------------------------- h = LN(h + relu(h@ff1.T)@ff2.T+b) ; 64 rows x 4 waves
__global__ __launch_bounds__(256, 4) void k_ffln(const float* __restrict__ ff1,
                                                 const float* __restrict__ b1,
                                                 const float* __restrict__ Tff2,
                                                 const float* __restrict__ b2,
                                                 const float* __restrict__ g,
                                                 const float* __restrict__ beta,
                                                 float* __restrict__ h) {
    __shared__ float hid[64][129];  // bank = (r + j) % 32: conflict-free
    __shared__ float ps[4][64], pq[4][64];
    int tid = threadIdx.x;
    int w = tid >> 6, r = tid & 63;
    size_t rowid = (size_t)blockIdx.x * 64 + r;
    float hr[72];
    const float4* hv = (const float4*)(h + rowid * 72);
#pragma unroll
    for (int k = 0; k < 18; ++k) {
        float4 v = hv[k];
        hr[4 * k] = v.x; hr[4 * k + 1] = v.y; hr[4 * k + 2] = v.z; hr[4 * k + 3] = v.w;
    }
    int j0 = w * 32;
    for (int jj = 0; jj < 32; ++jj) {
        int j = j0 + jj;
        float a = b1[j];
        const float* wp = ff1 + (size_t)j * 72;
#pragma unroll
        for (int i = 0; i < 72; ++i) a = fmaf(hr[i], wp[i], a);
        hid[r][j] = fmaxf(a, 0.f);
    }
    __syncthreads();
    int o0 = w * 18;
    float acc[18];
#pragma unroll
    for (int o = 0; o < 18; ++o) acc[o] = b2[o0 + o];
    for (int j = 0; j < 128; ++j) {
        float hj = hid[r][j];
        const float* wt = Tff2 + (size_t)j * 72 + o0;
#pragma unroll
        for (int o = 0; o < 18; ++o) acc[o] = fmaf(hj, wt[o], acc[o]);
    }
    const float* hres = h + rowid * 72 + o0;
    float s = 0.f, q = 0.f;
#pragma unroll
    for (int o = 0; o < 18; ++o) {
        acc[o] += hres[o];
        s += acc[o];
        q = fmaf(acc[o], acc[o], q);
    }
    ps[w][r] = s; pq[w][r] = q;
    __syncthreads();
    float st = ps[0][r] + ps[1][r] + ps[2][r] + ps[3][r];
    float qt = pq[0][r] + pq[1][r] + pq[2][r] + pq[3][r];
    float mu = st / 72.0f;
    float var = fmaxf(qt / 72.0f - mu * mu, 0.0f);
    float rstd = 1.0f / sqrtf(var + 1e-5f);
    float* hw = h + rowid * 72 + o0;
#pragma unroll
    for (int o = 0; o < 18; ++o) hw[o] = (acc[o] - mu) * rstd * g[o0 + o] + beta[o0 + o];
}

// ---------------------------------------------------------------- masked mean-pool + static emb + 2-layer MLP
__global__ void k_head(const float* __restrict__ h, const int* __restrict__ lengths,
                       const float* __restrict__ statics, const float* __restrict__ W_emb,
                       const float* __restrict__ b_emb, const float* __restrict__ w1,
                       const float* __restrict__ bb1, const float* __restrict__ w2,
                       const float* __restrict__ bb2, float* __restrict__ out) {
    __shared__ float ps2[4][72];
    __shared__ float feat[108];
    __shared__ float hidm[108];
    __shared__ float st[9];
    int b = blockIdx.x, tid = threadIdx.x;
    int w = tid >> 6, lane = tid & 63;
    int len = lengths[b];
    if (tid < 9) st[tid] = statics[b * 9 + tid];
    for (int idx = tid; idx < 288; idx += 256) ((float*)ps2)[idx] = 0.f;
    __syncthreads();
#pragma unroll
    for (int c0 = 0; c0 < 128; c0 += 64) {
        int col = c0 + lane;
        if (col < 72) {
            float s = 0.f;
            for (int t = w; t < len; t += 4) s += h[((size_t)t * BB + b) * 72 + col];
            ps2[w][col] = s;
        }
    }
    __syncthreads();
    if (tid < 72)
        feat[tid] = (ps2[0][tid] + ps2[1][tid] + ps2[2][tid] + ps2[3][tid]) / ((float)len + 1.0f);
    if (tid >= 128 && tid < 164) {
        int o = tid - 128;
        float a = b_emb[o];
#pragma unroll
        for (int i = 0; i < 9; ++i) a = fmaf(st[i], W_emb[o * 9 + i], a);
        feat[72 + o] = a;
    }
    __syncthreads();
    if (tid < 108) {
        float a = bb1[tid];
        for (int i = 0; i < 108; ++i) a = fmaf(feat[i], w1[tid * 108 + i], a);
        hidm[tid] = fmaxf(a, 0.f);
    }
    __syncthreads();
    if (tid < 2) {
        float a = bb2[tid];
        for (int i = 0; i < 108; ++i) a = fmaf(hidm[i], w2[tid * 108 + i], a);
        out[b * 2 + tid] = a;
    }
}

// ---------------------------------------------------------------- final distance reduce
__global__ void k_dist(const float* __restrict__ rowsum, float* __restrict__ out) {
    __shared__ float red[256];
    int tid = threadIdx.x;
    red[tid] = rowsum[tid];
    __syncthreads();
    for (int s = 128; s > 0; s >>= 1) { if (tid < s) red[tid] += red[tid + s]; __syncthreads(); }
    if (tid == 0) out[2 * BB] = red[0] / 65536.0f;
}

extern "C" void kernel_launch(void* const* d_in, const int* in_sizes, int n_in,
                              void* d_out, int out_size, void* d_ws, size_t ws_size,
                              hipStream_t stream) {
    const float* src     = (const float*)d_in[0];
    const float* statics = (const float*)d_in[1];
    const float* times   = (const float*)d_in[2];
    const int*   lengths = (const int*)d_in[3];
    const float* W_enc = (const float*)d_in[4];  const float* b_enc = (const float*)d_in[5];
    const float* W_emb = (const float*)d_in[6];  const float* b_emb = (const float*)d_in[7];
    const float* Wq = (const float*)d_in[8];     const float* bq = (const float*)d_in[9];
    const float* Wk = (const float*)d_in[10];    const float* bk = (const float*)d_in[11];
    const float* Wv = (const float*)d_in[12];    const float* bv = (const float*)d_in[13];
    const float* Wskip = (const float*)d_in[14]; const float* bskip = (const float*)d_in[15];
    const float* enc_in_w = (const float*)d_in[16];  const float* enc_in_b = (const float*)d_in[17];
    const float* enc_out_w = (const float*)d_in[18]; const float* enc_out_b = (const float*)d_in[19];
    const float* ff1_w = (const float*)d_in[20]; const float* ff1_b = (const float*)d_in[21];
    const float* ff2_w = (const float*)d_in[22]; const float* ff2_b = (const float*)d_in[23];
    const float* ln1_g = (const float*)d_in[24]; const float* ln1_b = (const float*)d_in[25];
    const float* ln2_g = (const float*)d_in[26]; const float* ln2_b = (const float*)d_in[27];
    const float* w1 = (const float*)d_in[28];    const float* bb1 = (const float*)d_in[29];
    const float* w2 = (const float*)d_in[30];    const float* bb2 = (const float*)d_in[31];
    float* out = (float*)d_out;

    float* p = (float*)d_ws;
    float* x    = p; p += (size_t)ROWS * 36;
    float* h    = p; p += (size_t)ROWS * 72;
    float* qkv  = p; p += (size_t)ROWS * 216;
    float* ctx  = p; p += (size_t)ROWS * 72;
    float* qg   = p; p += (size_t)36 * BB * 36;
    float* kg   = p; p += (size_t)36 * BB * 36;
    float* vg   = p; p += (size_t)36 * BB * 36;
    float* Abuf = p; p += (size_t)BB * 1296;
    float* sqv  = p; p += BB;
    float* rsum = p; p += BB;
    float* ts   = p; p += 32;
    float* T_ff2 = p; p += 2 * 9216;

    k_prep<<<72, 256, 0, stream>>>(ff2_w, T_ff2, ts);
    k_enc1<<<dim3(TT, 4), 256, 0, stream>>>(src, W_enc, b_enc, x);
    k_enc2<<<dim3(TT, 4), 256, 0, stream>>>(x, Wskip, bskip, h);
    k_pe<<<(ROWS * 36) / 256, 256, 0, stream>>>(times, ts, h);
    k_graph_qkv<<<dim3(36, 12), 256, 0, stream>>>(x, Wq, bq, Wk, bk, Wv, bv, qg, kg, vg);
    k_graph_attn<<<BB, 128, 0, stream>>>(qg, kg, vg, h, Abuf, sqv);
    k_gram<<<BB, 256, 0, stream>>>(Abuf, sqv, rsum);
    for (int l = 0; l < 2; ++l) {
        k_qkv<<<dim3(TT, 8), 256, 0, stream>>>(h, enc_in_w + (size_t)l * 216 * 72,
                                               enc_in_b + l * 216, qkv);
        k_attn<<<BB * 4, 256, 0, stream>>>(qkv, lengths, ctx);
        k_outln<<<ROWS / 64, 256, 0, stream>>>(ctx, enc_out_w + (size_t)l * 5184, enc_out_b + l * 72,
                                               ln1_g + l * 72, ln1_b + l * 72, h);
        k_ffln<<<ROWS / 64, 256, 0, stream>>>(ff1_w + (size_t)l * 128 * 72, ff1_b + l * 128,
                                              T_ff2 + (size_t)l * 9216, ff2_b + l * 72,
                                              ln2_g + l * 72, ln2_b + l * 72, h);
    }
    k_head<<<BB, 256, 0, stream>>>(h, lengths, statics, W_emb, b_emb, w1, bb1, w2, bb2, out);
    k_dist<<<1, 256, 0, stream>>>(rsum, out);
}

// Round 5
// 867.253 us; speedup vs baseline: 1.6879x; 1.6173x over previous
//
#include <hip/hip_runtime.h>

#define TT 215
#define BB 256
#define ROWS (TT * BB)  // 55040 = 860 * 64

// ---------------------------------------------------------------- one-shot prep: ff2 transpose + timescales
__global__ void k_prep(const float* __restrict__ ff2_w, float* __restrict__ T_ff2,
                       float* __restrict__ ts) {
    int g = blockIdx.x * 256 + threadIdx.x;
    if (g < 18) ts[g] = (float)pow(215.0, (double)g / 17.0);  // matches np float64 215**linspace
    if (g < 2 * 9216) {  // ff2 [2][72][128] -> [2][j][o]
        int l = g / 9216, e = g % 9216;
        int o = e / 128, j = e % 128;
        T_ff2[l * 9216 + j * 72 + o] = ff2_w[g];
    }
}

// ---------------------------------------------------------------- x = (src[:,:,:36] @ W_enc.T + b)*6 ; grid (215,4)
__global__ __launch_bounds__(256, 1) void k_enc1(const float* __restrict__ src,
                                                 const float* __restrict__ W,
                                                 const float* __restrict__ bias,
                                                 float* __restrict__ x) {
    int row = blockIdx.x * 256 + threadIdx.x;
    int o0 = blockIdx.y * 9;
    float s[36];
    const float4* sv = (const float4*)(src + (size_t)row * 72);
#pragma unroll
    for (int k = 0; k < 9; ++k) {
        float4 v = sv[k];
        s[4 * k] = v.x; s[4 * k + 1] = v.y; s[4 * k + 2] = v.z; s[4 * k + 3] = v.w;
    }
    float* xp = x + (size_t)row * 36 + o0;
#pragma unroll
    for (int o = 0; o < 9; ++o) {
        float a = bias[o0 + o];
        const float* w = W + (size_t)(o0 + o) * 36;
#pragma unroll
        for (int i = 0; i < 36; ++i) a = fmaf(s[i], w[i], a);
        xp[o] = a * 6.0f;
    }
}

// ---------------------------------------------------------------- h[:,:, :36] = x @ Wskip.T + b ; grid (215,4)
__global__ __launch_bounds__(256, 1) void k_enc2(const float* __restrict__ x,
                                                 const float* __restrict__ W,
                                                 const float* __restrict__ bias,
                                                 float* __restrict__ h) {
    int row = blockIdx.x * 256 + threadIdx.x;
    int o0 = blockIdx.y * 9;
    float xr[36];
    const float4* xv = (const float4*)(x + (size_t)row * 36);
#pragma unroll
    for (int k = 0; k < 9; ++k) {
        float4 v = xv[k];
        xr[4 * k] = v.x; xr[4 * k + 1] = v.y; xr[4 * k + 2] = v.z; xr[4 * k + 3] = v.w;
    }
    float* hp = h + (size_t)row * 72 + o0;
#pragma unroll
    for (int o = 0; o < 9; ++o) {
        float a = bias[o0 + o];
        const float* w = W + (size_t)(o0 + o) * 36;
#pragma unroll
        for (int i = 0; i < 36; ++i) a = fmaf(xr[i], w[i], a);
        hp[o] = a;
    }
}

// ---------------------------------------------------------------- h[:,:,36:] = pe ; elementwise
__global__ __launch_bounds__(256) void k_pe(const float* __restrict__ times,
                                            const float* __restrict__ ts,
                                            float* __restrict__ h) {
    int idx = blockIdx.x * 256 + threadIdx.x;  // < ROWS*36
    int d = idx % 36, row = idx / 36;
    float t = times[row];
    float val;
    if (d < 18) val = sinf(t / ts[d]);
    else        val = cosf(t / ts[d - 18]);
    h[(size_t)row * 72 + 36 + d] = val;
}

// ---------------------------------------------------------------- graph q|k|v ; grid (36, 12): mat = y>>2, o0 = (y&3)*9
__global__ __launch_bounds__(256, 1) void k_graph_qkv(const float* __restrict__ x,
                                                      const float* __restrict__ Wq, const float* __restrict__ bq,
                                                      const float* __restrict__ Wk, const float* __restrict__ bk,
                                                      const float* __restrict__ Wv, const float* __restrict__ bv,
                                                      float* __restrict__ qg, float* __restrict__ kg,
                                                      float* __restrict__ vg) {
    int row = blockIdx.x * 256 + threadIdx.x;  // < 9216
    int mat = blockIdx.y >> 2;
    int o0 = (blockIdx.y & 3) * 9;
    const float* W; const float* bias; float* out;
    if (mat == 0)      { W = Wq; bias = bq; out = qg; }
    else if (mat == 1) { W = Wk; bias = bk; out = kg; }
    else               { W = Wv; bias = bv; out = vg; }
    float xr[36];
    const float4* xv = (const float4*)(x + (size_t)row * 36);
#pragma unroll
    for (int k = 0; k < 9; ++k) {
        float4 v = xv[k];
        xr[4 * k] = v.x; xr[4 * k + 1] = v.y; xr[4 * k + 2] = v.z; xr[4 * k + 3] = v.w;
    }
    float* op = out + (size_t)row * 36 + o0;
#pragma unroll
    for (int o = 0; o < 9; ++o) {
        float a = bias[o0 + o];
        const float* w = W + (size_t)(o0 + o) * 36;
#pragma unroll
        for (int i = 0; i < 36; ++i) a = fmaf(xr[i], w[i], a);
        op[o] = a;
    }
}

// ---------------------------------------------------------------- graph attention per batch; h[:36,:,:36] += msg
__global__ void k_graph_attn(const float* __restrict__ qg, const float* __restrict__ kg,
                             const float* __restrict__ vg, float* __restrict__ h,
                             float* __restrict__ Abuf, float* __restrict__ sqv) {
    __shared__ float q[1296], k[1296], v[1296], A[1296];
    __shared__ float red[128];
    int b = blockIdx.x, tid = threadIdx.x;
    for (int i = tid; i < 1296; i += 128) {
        int t = i / 36, e = i % 36;
        int g = (t * BB + b) * 36 + e;
        q[i] = qg[g]; k[i] = kg[g]; v[i] = vg[g];
    }
    __syncthreads();
    for (int i = tid; i < 1296; i += 128) {
        int r = i / 36, c = i % 36;
        float a = 0.f;
#pragma unroll
        for (int e = 0; e < 36; ++e) a = fmaf(q[r * 36 + e], k[c * 36 + e], a);
        A[i] = a * (1.0f / 6.0f);
    }
    __syncthreads();
    if (tid < 36) {
        float m = -1e30f;
        for (int j = 0; j < 36; ++j) m = fmaxf(m, A[tid * 36 + j]);
        float s = 0.f;
        for (int j = 0; j < 36; ++j) { float e = expf(A[tid * 36 + j] - m); A[tid * 36 + j] = e; s += e; }
        float inv = 1.0f / s;
        for (int j = 0; j < 36; ++j) A[tid * 36 + j] *= inv;
    }
    __syncthreads();
    float lsq = 0.f;
    for (int i = tid; i < 1296; i += 128) {
        float a = A[i];
        Abuf[(size_t)b * 1296 + i] = a;
        lsq = fmaf(a, a, lsq);
        int r = i / 36, e = i % 36;
        float m = 0.f;
#pragma unroll
        for (int j = 0; j < 36; ++j) m = fmaf(A[r * 36 + j], v[j * 36 + e], m);
        h[((size_t)r * BB + b) * 72 + e] += m;
    }
    red[tid] = lsq;
    __syncthreads();
    for (int s = 64; s > 0; s >>= 1) { if (tid < s) red[tid] += red[tid + s]; __syncthreads(); }
    if (tid == 0) sqv[b] = red[0];
}

// ---------------------------------------------------------------- Gram row + per-row distance partial sum
__global__ void k_gram(const float* __restrict__ Abuf, const float* __restrict__ sqv,
                       float* __restrict__ rowsum) {
    __shared__ float Arow[1296];
    __shared__ float red[256];
    int b1 = blockIdx.x, tid = threadIdx.x;
    for (int i = tid; i < 1296; i += 256) Arow[i] = Abuf[(size_t)b1 * 1296 + i];
    __syncthreads();
    int b2 = tid;
    const float* a2 = Abuf + (size_t)b2 * 1296;
    float dot = 0.f;
    for (int e = 0; e < 1296; ++e) dot = fmaf(Arow[e], a2[e], dot);
    float d2 = fmaxf(sqv[b1] + sqv[b2] - 2.0f * dot, 0.0f);
    red[tid] = (d2 > 0.0f) ? sqrtf(d2) : 0.0f;
    __syncthreads();
    for (int s = 128; s > 0; s >>= 1) { if (tid < s) red[tid] += red[tid + s]; __syncthreads(); }
    if (tid == 0) rowsum[b1] = red[0];
}

// ---------------------------------------------------------------- qkv = h @ W_in.T + b_in ; grid (215,8), 27 outs
__global__ __launch_bounds__(256, 1) void k_qkv(const float* __restrict__ h, const float* __restrict__ W,
                                                const float* __restrict__ bias, float* __restrict__ qkv) {
    int row = blockIdx.x * 256 + threadIdx.x;
    int o0 = blockIdx.y * 27;
    float hr[72];
    const float4* hv = (const float4*)(h + (size_t)row * 72);
#pragma unroll
    for (int k = 0; k < 18; ++k) {
        float4 v = hv[k];
        hr[4 * k] = v.x; hr[4 * k + 1] = v.y; hr[4 * k + 2] = v.z; hr[4 * k + 3] = v.w;
    }
    float* qr = qkv + (size_t)row * 216 + o0;
    for (int c = 0; c < 9; ++c) {  // chunks of 3 outputs limit live weight values
        int j0 = o0 + c * 3;
        float a0 = bias[j0], a1 = bias[j0 + 1], a2 = bias[j0 + 2];
        const float* w0 = W + (size_t)j0 * 72;
#pragma unroll
        for (int i = 0; i < 72; ++i) {
            a0 = fmaf(hr[i], w0[i], a0);
            a1 = fmaf(hr[i], w0[72 + i], a1);
            a2 = fmaf(hr[i], w0[144 + i], a2);
        }
        qr[c * 3] = a0; qr[c * 3 + 1] = a1; qr[c * 3 + 2] = a2;
    }
}

// ---------------------------------------------------------------- masked MHA, block = (b, head), thread = query row
__global__ __launch_bounds__(256) void k_attn(const float* __restrict__ qkv,
                                              const int* __restrict__ lengths,
                                              float* __restrict__ ctx) {
    __shared__ float Ks[TT * 20];
    __shared__ float Vs[TT * 20];
    int b = blockIdx.x & (BB - 1);
    int hh = blockIdx.x >> 8;
    int tid = threadIdx.x;
    int len = lengths[b];
    for (int i = tid; i < TT * 20; i += 256) {
        int s = i / 20, d = i % 20;
        float kk = 0.f, vv = 0.f;
        if (d < 18) {
            size_t base = ((size_t)s * BB + b) * 216 + hh * 18 + d;
            kk = qkv[base + 72];
            vv = qkv[base + 144];
        }
        Ks[i] = kk; Vs[i] = vv;
    }
    __syncthreads();
    if (tid >= TT) return;
    float q[20];
    q[18] = 0.f; q[19] = 0.f;
    {
        const float* qb = qkv + ((size_t)tid * BB + b) * 216 + hh * 18;
#pragma unroll
        for (int d = 0; d < 18; ++d) q[d] = qb[d];
    }
    const float scale = 0.23570226039551587f;  // 1/sqrt(18)
    float m = -1e30f, l = 0.f;
    float acc[20];
#pragma unroll
    for (int d = 0; d < 20; ++d) acc[d] = 0.f;
    for (int s = 0; s < len; ++s) {
        const float4* kp = (const float4*)(Ks + s * 20);
        float sc = 0.f;
#pragma unroll
        for (int c = 0; c < 5; ++c) {
            float4 kv = kp[c];
            sc = fmaf(q[4 * c], kv.x, sc);
            sc = fmaf(q[4 * c + 1], kv.y, sc);
            sc = fmaf(q[4 * c + 2], kv.z, sc);
            sc = fmaf(q[4 * c + 3], kv.w, sc);
        }
        sc *= scale;
        float mn = fmaxf(m, sc);
        float alpha = __expf(m - mn);
        float p = __expf(sc - mn);
        l = l * alpha + p;
        const float4* vp = (const float4*)(Vs + s * 20);
#pragma unroll
        for (int c = 0; c < 5; ++c) {
            float4 vv = vp[c];
            acc[4 * c]     = fmaf(acc[4 * c], alpha, p * vv.x);
            acc[4 * c + 1] = fmaf(acc[4 * c + 1], alpha, p * vv.y);
            acc[4 * c + 2] = fmaf(acc[4 * c + 2], alpha, p * vv.z);
            acc[4 * c + 3] = fmaf(acc[4 * c + 3], alpha, p * vv.w);
        }
        m = mn;
    }
    float inv = 1.0f / l;
    float* cb = ctx + ((size_t)tid * BB + b) * 72 + hh * 18;
#pragma unroll
    for (int d = 0; d < 18; ++d) cb[d] = acc[d] * inv;
}

// ---------------------------------------------------------------- h = LN(h + ctx@Wout.T+b) ; 64 rows x 4 out-waves
__global__ __launch_bounds__(256, 1) void k_outln(const float* __restrict__ ctx,
                                                  const float* __restrict__ W,
                                                  const float* __restrict__ bias,
                                                  const float* __restrict__ g,
                                                  const float* __restrict__ beta,
                                                  float* __restrict__ h) {
    __shared__ float ps[4][64], pq[4][64];
    int tid = threadIdx.x;
    int w = __builtin_amdgcn_readfirstlane(tid >> 6);  // wave-uniform -> s_load weights
    int r = tid & 63;
    size_t rowid = (size_t)blockIdx.x * 64 + r;
    int o0 = w * 18;
    float cr[72];
    const float4* cv = (const float4*)(ctx + rowid * 72);
#pragma unroll
    for (int k = 0; k < 18; ++k) {
        float4 v = cv[k];
        cr[4 * k] = v.x; cr[4 * k + 1] = v.y; cr[4 * k + 2] = v.z; cr[4 * k + 3] = v.w;
    }
    float acc[18];
#pragma unroll
    for (int oo = 0; oo < 18; oo += 3) {  // chunks of 3 limit live weight values
        int j0 = o0 + oo;
        float a0 = bias[j0], a1 = bias[j0 + 1], a2 = bias[j0 + 2];
        const float* w0 = W + (size_t)j0 * 72;
#pragma unroll
        for (int i = 0; i < 72; ++i) {
            a0 = fmaf(cr[i], w0[i], a0);
            a1 = fmaf(cr[i], w0[72 + i], a1);
            a2 = fmaf(cr[i], w0[144 + i], a2);
        }
        acc[oo] = a0; acc[oo + 1] = a1; acc[oo + 2] = a2;
    }
    const float* hres = h + rowid * 72 + o0;
    float s = 0.f, q = 0.f;
#pragma unroll
    for (int o = 0; o < 18; ++o) {
        acc[o] += hres[o];
        s += acc[o];
        q = fmaf(acc[o], acc[o], q);
    }
    ps[w][r] = s; pq[w][r] = q;
    __syncthreads();
    float st = ps[0][r] + ps[1][r] + ps[2][r] + ps[3][r];
    float qt = pq[0][r] + pq[1][r] + pq[2][r] + pq[3][r];
    float mu = st / 72.0f;
    float var = fmaxf(qt / 72.0f - mu * mu, 0.0f);
    float rstd = 1.0f / sqrtf(var + 1e-5f);
    float* hw = h + rowid * 72 + o0;
#pragma unroll
    for (int o = 0; o < 18; ++o) hw[o] = (acc[o] - mu) * rstd * g[o0 + o] + beta[o0 + o];
}

// ---------------------------------------------------------------- h = LN(h + relu(h@ff1.T)@ff2.T+b) ; 64 rows x 4 waves
__global__ __launch_bounds__(256, 1) void k_ffln(const float* __restrict__ ff1,
                                                 const float* __restrict__ b1,
                                                 const float* __restrict__ Tff2,
                                                 const float* __restrict__ b2,
                                                 const float* __restrict__ g,
                                                 const float* __restrict__ beta,
                                                 float* __restrict__ h) {
    __shared__ float hid[64][129];  // bank = (r + j) % 32: conflict-free
    __shared__ float ps[4][64], pq[4][64];
    int tid = threadIdx.x;
    int w = __builtin_amdgcn_readfirstlane(tid >> 6);  // wave-uniform -> s_load weights
    int r = tid & 63;
    size_t rowid = (size_t)blockIdx.x * 64 + r;
    float hr[72];
    const float4* hv = (const float4*)(h + rowid * 72);
#pragma unroll
    for (int k = 0; k < 18; ++k) {
        float4 v = hv[k];
        hr[4 * k] = v.x; hr[4 * k + 1] = v.y; hr[4 * k + 2] = v.z; hr[4 * k + 3] = v.w;
    }
    int j0 = w * 32;
    for (int jj = 0; jj < 32; jj += 2) {  // pairs limit live weight values
        int j = j0 + jj;
        float a0 = b1[j], a1 = b1[j + 1];
        const float* wp = ff1 + (size_t)j * 72;
#pragma unroll
        for (int i = 0; i < 72; ++i) {
            a0 = fmaf(hr[i], wp[i], a0);
            a1 = fmaf(hr[i], wp[72 + i], a1);
        }
        hid[r][j] = fmaxf(a0, 0.f);
        hid[r][j + 1] = fmaxf(a1, 0.f);
    }
    __syncthreads();
    int o0 = w * 18;
    float acc[18];
#pragma unroll
    for (int o = 0; o < 18; ++o) acc[o] = b2[o0 + o];
    for (int j = 0; j < 128; ++j) {
        float hj = hid[r][j];
        const float* wt = Tff2 + (size_t)j * 72 + o0;
#pragma unroll
        for (int o = 0; o < 18; ++o) acc[o] = fmaf(hj, wt[o], acc[o]);
    }
    const float* hres = h + rowid * 72 + o0;
    float s = 0.f, q = 0.f;
#pragma unroll
    for (int o = 0; o < 18; ++o) {
        acc[o] += hres[o];
        s += acc[o];
        q = fmaf(acc[o], acc[o], q);
    }
    ps[w][r] = s; pq[w][r] = q;
    __syncthreads();
    float st = ps[0][r] + ps[1][r] + ps[2][r] + ps[3][r];
    float qt = pq[0][r] + pq[1][r] + pq[2][r] + pq[3][r];
    float mu = st / 72.0f;
    float var = fmaxf(qt / 72.0f - mu * mu, 0.0f);
    float rstd = 1.0f / sqrtf(var + 1e-5f);
    float* hw = h + rowid * 72 + o0;
#pragma unroll
    for (int o = 0; o < 18; ++o) hw[o] = (acc[o] - mu) * rstd * g[o0 + o] + beta[o0 + o];
}

// ---------------------------------------------------------------- masked mean-pool + static emb + 2-layer MLP
__global__ void k_head(const float* __restrict__ h, const int* __restrict__ lengths,
                       const float* __restrict__ statics, const float* __restrict__ W_emb,
                       const float* __restrict__ b_emb, const float* __restrict__ w1,
                       const float* __restrict__ bb1, const float* __restrict__ w2,
                       const float* __restrict__ bb2, float* __restrict__ out) {
    __shared__ float ps2[4][72];
    __shared__ float feat[108];
    __shared__ float hidm[108];
    __shared__ float st[9];
    int b = blockIdx.x, tid = threadIdx.x;
    int w = tid >> 6, lane = tid & 63;
    int len = lengths[b];
    if (tid < 9) st[tid] = statics[b * 9 + tid];
    for (int idx = tid; idx < 288; idx += 256) ((float*)ps2)[idx] = 0.f;
    __syncthreads();
#pragma unroll
    for (int c0 = 0; c0 < 128; c0 += 64) {
        int col = c0 + lane;
        if (col < 72) {
            float s = 0.f;
            for (int t = w; t < len; t += 4) s += h[((size_t)t * BB + b) * 72 + col];
            ps2[w][col] = s;
        }
    }
    __syncthreads();
    if (tid < 72)
        feat[tid] = (ps2[0][tid] + ps2[1][tid] + ps2[2][tid] + ps2[3][tid]) / ((float)len + 1.0f);
    if (tid >= 128 && tid < 164) {
        int o = tid - 128;
        float a = b_emb[o];
#pragma unroll
        for (int i = 0; i < 9; ++i) a = fmaf(st[i], W_emb[o * 9 + i], a);
        feat[72 + o] = a;
    }
    __syncthreads();
    if (tid < 108) {
        float a = bb1[tid];
        for (int i = 0; i < 108; ++i) a = fmaf(feat[i], w1[tid * 108 + i], a);
        hidm[tid] = fmaxf(a, 0.f);
    }
    __syncthreads();
    if (tid < 2) {
        float a = bb2[tid];
        for (int i = 0; i < 108; ++i) a = fmaf(hidm[i], w2[tid * 108 + i], a);
        out[b * 2 + tid] = a;
    }
}

// ---------------------------------------------------------------- final distance reduce
__global__ void k_dist(const float* __restrict__ rowsum, float* __restrict__ out) {
    __shared__ float red[256];
    int tid = threadIdx.x;
    red[tid] = rowsum[tid];
    __syncthreads();
    for (int s = 128; s > 0; s >>= 1) { if (tid < s) red[tid] += red[tid + s]; __syncthreads(); }
    if (tid == 0) out[2 * BB] = red[0] / 65536.0f;
}

extern "C" void kernel_launch(void* const* d_in, const int* in_sizes, int n_in,
                              void* d_out, int out_size, void* d_ws, size_t ws_size,
                              hipStream_t stream) {
    const float* src     = (const float*)d_in[0];
    const float* statics = (const float*)d_in[1];
    const float* times   = (const float*)d_in[2];
    const int*   lengths = (const int*)d_in[3];
    const float* W_enc = (const float*)d_in[4];  const float* b_enc = (const float*)d_in[5];
    const float* W_emb = (const float*)d_in[6];  const float* b_emb = (const float*)d_in[7];
    const float* Wq = (const float*)d_in[8];     const float* bq = (const float*)d_in[9];
    const float* Wk = (const float*)d_in[10];    const float* bk = (const float*)d_in[11];
    const float* Wv = (const float*)d_in[12];    const float* bv = (const float*)d_in[13];
    const float* Wskip = (const float*)d_in[14]; const float* bskip = (const float*)d_in[15];
    const float* enc_in_w = (const float*)d_in[16];  const float* enc_in_b = (const float*)d_in[17];
    const float* enc_out_w = (const float*)d_in[18]; const float* enc_out_b = (const float*)d_in[19];
    const float* ff1_w = (const float*)d_in[20]; const float* ff1_b = (const float*)d_in[21];
    const float* ff2_w = (const float*)d_in[22]; const float* ff2_b = (const float*)d_in[23];
    const float* ln1_g = (const float*)d_in[24]; const float* ln1_b = (const float*)d_in[25];
    const float* ln2_g = (const float*)d_in[26]; const float* ln2_b = (const float*)d_in[27];
    const float* w1 = (const float*)d_in[28];    const float* bb1 = (const float*)d_in[29];
    const float* w2 = (const float*)d_in[30];    const float* bb2 = (const float*)d_in[31];
    float* out = (float*)d_out;

    float* p = (float*)d_ws;
    float* x    = p; p += (size_t)ROWS * 36;
    float* h    = p; p += (size_t)ROWS * 72;
    float* qkv  = p; p += (size_t)ROWS * 216;
    float* ctx  = p; p += (size_t)ROWS * 72;
    float* qg   = p; p += (size_t)36 * BB * 36;
    float* kg   = p; p += (size_t)36 * BB * 36;
    float* vg   = p; p += (size_t)36 * BB * 36;
    float* Abuf = p; p += (size_t)BB * 1296;
    float* sqv  = p; p += BB;
    float* rsum = p; p += BB;
    float* ts   = p; p += 32;
    float* T_ff2 = p; p += 2 * 9216;

    k_prep<<<72, 256, 0, stream>>>(ff2_w, T_ff2, ts);
    k_enc1<<<dim3(TT, 4), 256, 0, stream>>>(src, W_enc, b_enc, x);
    k_enc2<<<dim3(TT, 4), 256, 0, stream>>>(x, Wskip, bskip, h);
    k_pe<<<(ROWS * 36) / 256, 256, 0, stream>>>(times, ts, h);
    k_graph_qkv<<<dim3(36, 12), 256, 0, stream>>>(x, Wq, bq, Wk, bk, Wv, bv, qg, kg, vg);
    k_graph_attn<<<BB, 128, 0, stream>>>(qg, kg, vg, h, Abuf, sqv);
    k_gram<<<BB, 256, 0, stream>>>(Abuf, sqv, rsum);
    for (int l = 0; l < 2; ++l) {
        k_qkv<<<dim3(TT, 8), 256, 0, stream>>>(h, enc_in_w + (size_t)l * 216 * 72,
                                               enc_in_b + l * 216, qkv);
        k_attn<<<BB * 4, 256, 0, stream>>>(qkv, lengths, ctx);
        k_outln<<<ROWS / 64, 256, 0, stream>>>(ctx, enc_out_w + (size_t)l * 5184, enc_out_b + l * 72,
                                               ln1_g + l * 72, ln1_b + l * 72, h);
        k_ffln<<<ROWS / 64, 256, 0, stream>>>(ff1_w + (size_t)l * 128 * 72, ff1_b + l * 128,
                                              T_ff2 + (size_t)l * 9216, ff2_b + l * 72,
                                              ln2_g + l * 72, ln2_b + l * 72, h);
    }
    k_head<<<BB, 256, 0, stream>>>(h, lengths, statics, W_emb, b_emb, w1, bb1, w2, bb2, out);
    k_dist<<<1, 256, 0, stream>>>(rsum, out);
}